// Round 2
// baseline (725.893 us; speedup 1.0000x reference)
//
#include <hip/hip_runtime.h>

// Conv2D 7x7 VALID, fp32, 8192x8192 -> 8186x8186. Memory-bound target.
// Persistent vertical-strip blocks: 64-wide strip, loop over 22 chunks of 64
// output rows. Double-buffered LDS staged with global_load_lds (width 16),
// stage(t+1) issued before compute(t) -> 2-phase software pipeline.

#define IH 8192
#define IW 8192
#define OH 8186
#define OW 8186

#define TW 64              // strip (output tile) width
#define CH 64              // output rows per chunk
#define LDS_STRIDE 76      // floats per staged row (>=70, 4*stride%32==16)
#define BUF_FLOATS 5376    // 21 x 1KB wave-chunks (covers 70*76=5320 floats)
#define NLDSCHUNK 21       // 1KB chunks per stage
#define NSEG 6
#define SEG_ROWS 1365      // ceil(8186/6)
#define NT 22              // chunks per segment: ceil(1365/64)

#define GLOAD_LDS(gp, lp) __builtin_amdgcn_global_load_lds( \
    (const __attribute__((address_space(1))) void*)(gp),    \
    (__attribute__((address_space(3))) void*)(lp), 16, 0, 0)

__global__ __launch_bounds__(256, 3)
void conv7x7_pipe(const float* __restrict__ x,
                  const float* __restrict__ wgt,
                  const float* __restrict__ bias,
                  float* __restrict__ out) {
    __shared__ float tile[2 * BUF_FLOATS];   // 43008 B -> 3 blocks/CU

    const int tid = threadIdx.x;

    // XCD-aware swizzle: 768 blocks = 8 XCDs x 96; seg-minor so each XCD owns
    // 16 adjacent strips (horizontal + vertical halo L2 reuse).
    const int bid = blockIdx.x;
    const int nb = (bid & 7) * 96 + (bid >> 3);
    const int strip = nb / NSEG;
    const int seg   = nb - strip * NSEG;
    const int C  = strip * TW;
    const int R0 = seg * SEG_ROWS;
    const int Rend = (R0 + SEG_ROWS < OH) ? (R0 + SEG_ROWS) : OH;

    // ---- weights: uniform -> SGPRs ----
    float w[49];
#pragma unroll
    for (int i = 0; i < 49; ++i) w[i] = wgt[i];
    const float b0 = bias[0];

    // ---- staging geometry (constant across chunks) ----
    // Wave wv stages 1KB chunks c = wv, wv+4, ... (<21). Lane ln covers
    // floats flat = c*256 + ln*4 .. +3 of the buffer; row=flat/76 col=flat%76.
    const int wv = tid >> 6;
    const int ln = tid & 63;
    int rowk[6];
    const float* gpk[6];          // x + clamped global column (row added later)
#pragma unroll
    for (int k = 0; k < 6; ++k) {
        const int c = wv + 4 * k;
        const int flat = c * 256 + ln * 4;
        const int row = flat / LDS_STRIDE;
        const int col = flat - row * LDS_STRIDE;
        rowk[k] = row;
        int gcol = C + col;
        gcol = (gcol > IW - 4) ? (IW - 4) : gcol;   // keep 16B load in-bounds
        gpk[k] = x + gcol;
    }

    auto stage = [&](int bufsel, int RB) {
#pragma unroll
        for (int k = 0; k < 6; ++k) {
            const int c = wv + 4 * k;
            if (c < NLDSCHUNK) {
                int grow = RB + rowk[k];
                grow = (grow > IH - 1) ? (IH - 1) : grow;
                const float* gp = gpk[k] + (size_t)grow * IW;
                GLOAD_LDS(gp, &tile[bufsel * BUF_FLOATS + c * 256]);
            }
        }
    };

    // ---- compute geometry: thread (tx,ty) owns 4x4 outputs ----
    const int tx = tid & 15;
    const int ty = tid >> 4;
    const int r0 = ty * 4;
    const int c0 = tx * 4;
    const int ocol = C + c0;

    // ---- prologue: stage chunk 0 ----
    stage(0, R0);
    __syncthreads();   // drains vmcnt(0): buf0 ready

    for (int t = 0; t < NT; ++t) {
        const int cur = t & 1;

        // issue next chunk's loads (async into other buffer)
        if (t + 1 < NT) stage(cur ^ 1, R0 + (t + 1) * CH);

        // ---- compute chunk t from tile[cur] ----
        float acc[4][4];
#pragma unroll
        for (int o = 0; o < 4; ++o)
#pragma unroll
            for (int oc = 0; oc < 4; ++oc) acc[o][oc] = 0.0f;

        const float* base = &tile[cur * BUF_FLOATS + r0 * LDS_STRIDE + c0];
#pragma unroll
        for (int ir = 0; ir < 10; ++ir) {
            const float4 fa = *reinterpret_cast<const float4*>(base + ir * LDS_STRIDE + 0);
            const float4 fb = *reinterpret_cast<const float4*>(base + ir * LDS_STRIDE + 4);
            const float4 fc = *reinterpret_cast<const float4*>(base + ir * LDS_STRIDE + 8);
            float f[12];
            f[0] = fa.x; f[1] = fa.y; f[2]  = fa.z; f[3]  = fa.w;
            f[4] = fb.x; f[5] = fb.y; f[6]  = fb.z; f[7]  = fb.w;
            f[8] = fc.x; f[9] = fc.y; f[10] = fc.z; f[11] = fc.w;

#pragma unroll
            for (int o = 0; o < 4; ++o) {
                const int wr = ir - o;           // kernel row for output row o
                if (wr < 0 || wr > 6) continue;  // compile-time after unroll
#pragma unroll
                for (int oc = 0; oc < 4; ++oc) {
#pragma unroll
                    for (int j = 0; j < 7; ++j) {
                        acc[o][oc] += f[oc + j] * w[wr * 7 + j];
                    }
                }
            }
        }

        // ---- store 4x4 micro-tile ----
        const int RB = R0 + t * CH;
#pragma unroll
        for (int o = 0; o < 4; ++o) {
            const int gr = RB + r0 + o;
            if (gr >= Rend) continue;
            float* orow_p = &out[(size_t)gr * OW + ocol];
            if (ocol + 3 < OW) {
                *reinterpret_cast<float2*>(orow_p + 0) =
                    make_float2(acc[o][0] + b0, acc[o][1] + b0);
                *reinterpret_cast<float2*>(orow_p + 2) =
                    make_float2(acc[o][2] + b0, acc[o][3] + b0);
            } else {
#pragma unroll
                for (int oc = 0; oc < 4; ++oc) {
                    if (ocol + oc < OW) orow_p[oc] = acc[o][oc] + b0;
                }
            }
        }

        // drains stage loads (vmcnt 0) + protects buffer reuse
        __syncthreads();
    }
}

extern "C" void kernel_launch(void* const* d_in, const int* in_sizes, int n_in,
                              void* d_out, int out_size, void* d_ws, size_t ws_size,
                              hipStream_t stream) {
    const float* x    = (const float*)d_in[0];
    const float* wgt  = (const float*)d_in[1];
    const float* bias = (const float*)d_in[2];
    float* out = (float*)d_out;

    conv7x7_pipe<<<dim3(128 * NSEG), 256, 0, stream>>>(x, wgt, bias, out);
}

// Round 3
// 553.112 us; speedup vs baseline: 1.3124x; 1.3124x over previous
//
#include <hip/hip_runtime.h>

// Conv2D 7x7 VALID, fp32, 8192x8192 -> 8186x8186.
// Row-band blocks: each block owns 64 output rows x 1024 cols, swept in 8
// chunks of 128 cols. Full-row writes => cache lines written once (no
// partial-line RMW from drifting strips). 2-phase global_load_lds pipeline,
// double-buffered LDS. Wave reads LDS as contiguous 512B runs (conflict-free).

#define IH 8192
#define IW 8192
#define OH 8186
#define OW 8186

#define BANDH 64          // output rows per band
#define TROWS 70          // staged input rows (64 + 6 halo)
#define CW 128            // output cols per chunk
#define TCOLS 136         // staged cols per chunk (128 + 6 halo + 2 pad)
#define NCH 8             // chunks per block
#define SEGW (CW * NCH)   // 1024 cols per block
#define NLC 38            // 1KB LDS wave-chunks: ceil(70*136/256)
#define BUF_FLOATS (NLC * 256)   // 9728 floats = 38912 B per buffer

__global__ __launch_bounds__(256, 2)
void conv7x7_band(const float* __restrict__ x,
                  const float* __restrict__ wgt,
                  const float* __restrict__ bias,
                  float* __restrict__ out) {
    __shared__ float tile[2 * BUF_FLOATS];   // 77824 B -> 2 blocks/CU

    const int tid = threadIdx.x;

    // XCD swizzle within each resident half (512 blocks): each XCD gets
    // 64 consecutive nb = 8 adjacent bands x all 8 hsegs.
    const int bid = blockIdx.x;
    const int g   = bid & 511;
    const int grp = bid >> 9;
    const int nb  = grp * 512 + (g & 7) * 64 + (g >> 3);
    const int band = nb >> 3;
    const int hseg = nb & 7;
    const int R  = band * BANDH;      // input/output row base
    const int CB = hseg * SEGW;       // col base of this block's sweep

    // ---- weights: uniform loads -> SGPRs ----
    float w[49];
#pragma unroll
    for (int i = 0; i < 49; ++i) w[i] = wgt[i];
    const float b0 = bias[0];

    // ---- staging geometry (rows fixed per block; cols shift per chunk) ----
    // Wave wv stages 1KB chunks c = wv, wv+4, ... (<38). Lane ln covers
    // buffer floats flat = c*256 + ln*4 ..+3; row = flat/136, col = flat%136.
    const int wv = tid >> 6;
    const int ln = tid & 63;
    unsigned rowbyte[10];
    int colk[10];
#pragma unroll
    for (int k = 0; k < 10; ++k) {
        const int c = wv + 4 * k;
        const int flat = c * 256 + ln * 4;
        const int row = flat / TCOLS;
        const int col = flat - row * TCOLS;
        int grow = R + row;
        if (grow > IH - 1) grow = IH - 1;           // band 127 tail clamp
        rowbyte[k] = (unsigned)grow * (unsigned)(IW * 4);
        colk[k] = col;
    }

    auto stage = [&](int bufsel, int Cc) {
#pragma unroll
        for (int k = 0; k < 10; ++k) {
            const int c = wv + 4 * k;
            if (c < NLC) {
                int gcol = Cc + colk[k];
                if (gcol > IW - 4) gcol = IW - 4;   // keep 16B load in-bounds
                const char* gp = (const char*)x + rowbyte[k] + (unsigned)gcol * 4u;
                __builtin_amdgcn_global_load_lds(
                    (const __attribute__((address_space(1))) void*)gp,
                    (__attribute__((address_space(3))) void*)
                        &tile[bufsel * BUF_FLOATS + c * 256],
                    16, 0, 0);
            }
        }
    };

    // ---- compute geometry: thread (tx,ty) owns 8 rows x 4 cols ----
    const int tx = tid & 31;
    const int ty = tid >> 5;
    const int r0 = ty * 8;
    const int orow0 = R + r0;

    // ---- prologue ----
    stage(0, CB);
    __syncthreads();   // vmcnt(0) drain: buf0 ready

    for (int t = 0; t < NCH; ++t) {
        const int cur = t & 1;
        if (t + 1 < NCH) stage(cur ^ 1, CB + (t + 1) * CW);   // async prefetch

        float acc[8][4];
#pragma unroll
        for (int o = 0; o < 8; ++o)
#pragma unroll
            for (int oc = 0; oc < 4; ++oc) acc[o][oc] = b0;   // bias folded in

        const float* base = &tile[cur * BUF_FLOATS + r0 * TCOLS + tx * 4];
#pragma unroll
        for (int ir = 0; ir < 14; ++ir) {
            const float4 fa = *reinterpret_cast<const float4*>(base + ir * TCOLS + 0);
            const float4 fb = *reinterpret_cast<const float4*>(base + ir * TCOLS + 4);
            const float4 fc = *reinterpret_cast<const float4*>(base + ir * TCOLS + 8);
            float f[12];
            f[0] = fa.x; f[1] = fa.y; f[2]  = fa.z; f[3]  = fa.w;
            f[4] = fb.x; f[5] = fb.y; f[6]  = fb.z; f[7]  = fb.w;
            f[8] = fc.x; f[9] = fc.y; f[10] = fc.z; f[11] = fc.w;

#pragma unroll
            for (int o = 0; o < 8; ++o) {
                const int wr = ir - o;           // kernel row for output row o
                if (wr < 0 || wr > 6) continue;  // compile-time after unroll
#pragma unroll
                for (int oc = 0; oc < 4; ++oc) {
#pragma unroll
                    for (int j = 0; j < 7; ++j) {
                        acc[o][oc] += f[oc + j] * w[wr * 7 + j];
                    }
                }
            }
        }

        // ---- store 8x4 micro-tile (rows contiguous with neighbors) ----
        const int ocol = CB + t * CW + tx * 4;
        const bool p0 = (ocol + 1) < OW;   // ocol <= 8184 (ocol always even)
        const bool p1 = (ocol + 3) < OW;
#pragma unroll
        for (int o = 0; o < 8; ++o) {
            const int gr = orow0 + o;
            if (gr < OH) {
                float* p = out + (size_t)gr * OW + ocol;
                if (p0) *reinterpret_cast<float2*>(p + 0) =
                    make_float2(acc[o][0], acc[o][1]);
                if (p1) *reinterpret_cast<float2*>(p + 2) =
                    make_float2(acc[o][2], acc[o][3]);
            }
        }

        __syncthreads();   // drains prefetch + protects buffer reuse
    }
}

extern "C" void kernel_launch(void* const* d_in, const int* in_sizes, int n_in,
                              void* d_out, int out_size, void* d_ws, size_t ws_size,
                              hipStream_t stream) {
    const float* x    = (const float*)d_in[0];
    const float* wgt  = (const float*)d_in[1];
    const float* bias = (const float*)d_in[2];
    float* out = (float*)d_out;

    conv7x7_band<<<dim3(128 * 8), 256, 0, stream>>>(x, wgt, bias, out);
}